// Round 19
// baseline (277.225 us; speedup 1.0000x reference)
//
#include <hip/hip_runtime.h>
#include <math.h>

#define NN 50000
#define NE 400000
#define SLOTS 48
#define MT2 196       // (NN+255)/256 row tiles
#define BXPG2 25      // ceil(MT2/8) row tiles per XCD group

typedef unsigned short u16;
typedef __bf16 bf16x8 __attribute__((ext_vector_type(8)));
typedef float f32x4 __attribute__((ext_vector_type(4)));
typedef u16 bfu8 __attribute__((ext_vector_type(8)));
typedef u16 bfu4 __attribute__((ext_vector_type(4)));

__device__ __forceinline__ u16 f2bf(float f) {
    unsigned u = __builtin_bit_cast(unsigned, f);
    u += 0x7fff + ((u >> 16) & 1);
    return (u16)(u >> 16);
}
__device__ __forceinline__ float bf2f(u16 h) {
    unsigned u = ((unsigned)h) << 16;
    return __builtin_bit_cast(float, u);
}

__device__ __forceinline__ void gload_lds16(const void* g, void* l) {
    typedef __attribute__((address_space(1))) const unsigned int GU;
    typedef __attribute__((address_space(3))) unsigned int LU;
    __builtin_amdgcn_global_load_lds((GU*)g, (LU*)l, 16, 0, 0);
}

// ---------------- conversions ----------------
// x f32 -> bf16 row-major (grid-stride, float4 -> bfu4)
__global__ void cvt_x(const float* __restrict__ in, u16* __restrict__ out, int total4) {
    const int stride = gridDim.x * blockDim.x;
    for (int i = blockIdx.x * blockDim.x + threadIdx.x; i < total4; i += stride) {
        float4 v = reinterpret_cast<const float4*>(in)[i];
        bfu4 o;
        o[0] = f2bf(v.x); o[1] = f2bf(v.y); o[2] = f2bf(v.z); o[3] = f2bf(v.w);
        reinterpret_cast<bfu4*>(out)[i] = o;
    }
}

__global__ void cvt_w(const float* __restrict__ W1, u16* __restrict__ Wt1,
                      const float* __restrict__ W2, u16* __restrict__ Wt2,
                      const float* __restrict__ W3, u16* __restrict__ Wt3) {
    int idx = blockIdx.x * blockDim.x + threadIdx.x;
    if (idx < 262144) {
        int n = idx >> 9, k = idx & 511;
        Wt1[idx] = f2bf(W1[(size_t)k * 512 + n]);
        return;
    }
    idx -= 262144;
    if (idx < 131072) {
        int n = idx >> 9, k = idx & 511;
        Wt2[idx] = f2bf(W2[(size_t)k * 256 + n]);
        return;
    }
    idx -= 131072;
    if (idx < 32768) {
        int n = idx >> 8, k = idx & 255;
        Wt3[idx] = f2bf(W3[(size_t)k * 128 + n]);
    }
}

// ---------------- ELL build ----------------
__global__ void init_ell(int* __restrict__ ell, int* __restrict__ cnt, int N) {
    int i = blockIdx.x * blockDim.x + threadIdx.x;
    if (i < N * SLOTS) ell[i] = N;
    if (i < N) cnt[i] = 0;
}

__global__ void build_ell(const int* __restrict__ src, const int* __restrict__ dst,
                          int* __restrict__ cnt, int* __restrict__ ell, int E) {
    int e = blockIdx.x * blockDim.x + threadIdx.x;
    if (e < E) {
        const int d = dst[e];
        int pos = atomicAdd(&cnt[d], 1);
        if (pos < SLOTS) ell[d * SLOTS + pos] = src[e];
    }
}

__global__ void make_dinv(const int* __restrict__ cnt, float* __restrict__ dinv, int N) {
    int i = blockIdx.x * blockDim.x + threadIdx.x;
    if (i < N) dinv[i] = rsqrtf(1.0f + (float)cnt[i]);
    if (i == 0) dinv[N] = 0.f;
}

// ---------------- bf16 MFMA GEMM: H = X @ Wt^T, BM=256 x BN=128, 8 waves ----
// XCD-grouped decode, 2-phase dbuf, one vmcnt(0)+barrier per K-step.
// LDS: A 2x16K @0, B 2x8K @32768 (48K total, 3 blocks/CU).
template <int NT, int KK>
__global__ __launch_bounds__(512) void gemm_bf16(
    const u16* __restrict__ X, const u16* __restrict__ Wt,
    u16* __restrict__ H, int N, int NO)
{
    const int k8 = blockIdx.x & 7;
    const int idx = blockIdx.x >> 3;
    const int bx = k8 * BXPG2 + idx / NT;
    const int nt = idx - (idx / NT) * NT;
    const int m0 = bx * 256;
    if (m0 >= N) return;
    const int n0 = nt * 128;

    __shared__ unsigned char lds[49152];
    const int tid = threadIdx.x;
    const int w = tid >> 6;
    const int lane = tid & 63;
    const int wr = w >> 1;
    const int wc = w & 1;

    f32x4 acc[4][4] = {};

    // B staging map: 8192B tile, 1 load/thread
    const int brow = tid >> 2;
    const int bgcol = (((tid & 3) ^ (brow & 3)) << 3);
    const int bgrow = n0 + brow;
    // A map: idx2=i*512+tid, r=idx2>>2, slot s=(tid&3)^(r&3)
    const int gcol = (((tid & 3) ^ ((tid >> 2) & 3)) << 3);
    int agrow2[2];
    #pragma unroll
    for (int i = 0; i < 2; ++i) {
        int rr = m0 + i * 128 + (tid >> 2);
        agrow2[i] = (rr < N) ? rr : N - 1;
    }

    #pragma unroll
    for (int i = 0; i < 2; ++i)
        gload_lds16(X + (size_t)agrow2[i] * KK + gcol,
                    lds + i * 8192 + w * 1024);
    gload_lds16(Wt + (size_t)bgrow * KK + bgcol, lds + 32768 + w * 1024);
    asm volatile("s_waitcnt vmcnt(0)" ::: "memory");
    __syncthreads();

    int cur = 0;
    for (int k0 = 0; k0 < KK; k0 += 32) {
        const bool more = (k0 + 32 < KK);
        if (more) {
            const int na = (cur ^ 1) * 16384;
            const int nb = 32768 + (cur ^ 1) * 8192;
            #pragma unroll
            for (int i = 0; i < 2; ++i)
                gload_lds16(X + (size_t)agrow2[i] * KK + k0 + 32 + gcol,
                            lds + na + i * 8192 + w * 1024);
            gload_lds16(Wt + (size_t)bgrow * KK + k0 + 32 + bgcol,
                        lds + nb + w * 1024);
        }

        const int ca = cur * 16384;
        const int cbb = 32768 + cur * 8192;
        bf16x8 af[4], bfr[4];
        #pragma unroll
        for (int m = 0; m < 4; ++m) {
            const int r = wr * 64 + m * 16 + (lane & 15);
            const int off = ca + r * 64 + (((lane >> 4) ^ (r & 3)) * 16);
            af[m] = *reinterpret_cast<const bf16x8*>(lds + off);
        }
        #pragma unroll
        for (int n = 0; n < 4; ++n) {
            const int r = wc * 64 + n * 16 + (lane & 15);
            const int off = cbb + r * 64 + (((lane >> 4) ^ (r & 3)) * 16);
            bfr[n] = *reinterpret_cast<const bf16x8*>(lds + off);
        }
        #pragma unroll
        for (int m = 0; m < 4; ++m)
            #pragma unroll
            for (int n = 0; n < 4; ++n)
                acc[m][n] = __builtin_amdgcn_mfma_f32_16x16x32_bf16(
                    af[m], bfr[n], acc[m][n], 0, 0, 0);

        asm volatile("s_waitcnt vmcnt(0)" ::: "memory");
        __syncthreads();
        cur ^= 1;
    }

    // epilogue: 4 quadrant passes (row-half rh x col-half c) via 33792B Cs
    float* Cs = reinterpret_cast<float*>(lds);
    #pragma unroll
    for (int rh = 0; rh < 2; ++rh) {
        #pragma unroll
        for (int c = 0; c < 2; ++c) {
            __syncthreads();
            if ((wr >> 1) == rh && wc == c) {
                const int rbase = (wr & 1) * 64;
                #pragma unroll
                for (int m = 0; m < 4; ++m)
                    #pragma unroll
                    for (int n = 0; n < 4; ++n)
                        #pragma unroll
                        for (int r = 0; r < 4; ++r) {
                            int row = rbase + m * 16 + (lane >> 4) * 4 + r;
                            int col = n * 16 + (lane & 15);
                            Cs[row * 66 + col] = acc[m][n][r];
                        }
            }
            __syncthreads();
            const int row = tid >> 2;        // 0..127
            const int q = tid & 3;           // 16-col quarter
            const int grow = m0 + rh * 128 + row;
            if (grow < N) {
                const float* p = Cs + row * 66 + q * 16;
                bfu8 oA, oB;
                #pragma unroll
                for (int j = 0; j < 8; ++j) oA[j] = f2bf(p[j]);
                #pragma unroll
                for (int j = 0; j < 8; ++j) oB[j] = f2bf(p[8 + j]);
                bfu8* dst = reinterpret_cast<bfu8*>(H + (size_t)grow * NO + n0 + c * 64 + q * 16);
                dst[0] = oA; dst[1] = oB;
            }
        }
    }
}

// ---------------- ELL pull-aggregate (bf16 H), 4-way MLP, 16B/lane ---------
template <int F, int LPN, bool BFOUT, bool SUMOUT>
__global__ __launch_bounds__(128) void aggregate_bf(
    const u16* __restrict__ H, const int* __restrict__ cnt,
    const int* __restrict__ ell, const float* __restrict__ dinv,
    const float* __restrict__ bias, void* __restrict__ Aout,
    float* __restrict__ partials, int N)
{
    constexpr int EPL = F / LPN;
    const int gtid = blockIdx.x * blockDim.x + threadIdx.x;
    const int node = gtid / LPN;
    const int lane = gtid - node * LPN;
    const int co = lane * EPL;
    const bool valid = node < N;

    float a0[EPL], a1[EPL], a2[EPL], a3[EPL];
    #pragma unroll
    for (int q = 0; q < EPL; ++q) { a0[q] = 0.f; a1[q] = 0.f; a2[q] = 0.f; a3[q] = 0.f; }

    if (valid) {
        const int base = node * SLOTS;
        const int c = min(cnt[node], SLOTS);
        const int pd = (c + 3) & ~3;
        for (int j = 0; j < pd; j += 4) {
            const int4 s4 = *reinterpret_cast<const int4*>(ell + base + j);
            const float d0 = dinv[s4.x];
            const float d1 = dinv[s4.y];
            const float d2 = dinv[s4.z];
            const float d3 = dinv[s4.w];
            if constexpr (EPL == 8) {
                bfu8 v0 = *reinterpret_cast<const bfu8*>(H + (size_t)s4.x * F + co);
                bfu8 v1 = *reinterpret_cast<const bfu8*>(H + (size_t)s4.y * F + co);
                bfu8 v2 = *reinterpret_cast<const bfu8*>(H + (size_t)s4.z * F + co);
                bfu8 v3 = *reinterpret_cast<const bfu8*>(H + (size_t)s4.w * F + co);
                #pragma unroll
                for (int q = 0; q < 8; ++q) {
                    a0[q] = fmaf(bf2f(v0[q]), d0, a0[q]);
                    a1[q] = fmaf(bf2f(v1[q]), d1, a1[q]);
                    a2[q] = fmaf(bf2f(v2[q]), d2, a2[q]);
                    a3[q] = fmaf(bf2f(v3[q]), d3, a3[q]);
                }
            } else {
                bfu4 v0 = *reinterpret_cast<const bfu4*>(H + (size_t)s4.x * F + co);
                bfu4 v1 = *reinterpret_cast<const bfu4*>(H + (size_t)s4.y * F + co);
                bfu4 v2 = *reinterpret_cast<const bfu4*>(H + (size_t)s4.z * F + co);
                bfu4 v3 = *reinterpret_cast<const bfu4*>(H + (size_t)s4.w * F + co);
                #pragma unroll
                for (int q = 0; q < EPL; ++q) {
                    a0[q] = fmaf(bf2f(v0[q]), d0, a0[q]);
                    a1[q] = fmaf(bf2f(v1[q]), d1, a1[q]);
                    a2[q] = fmaf(bf2f(v2[q]), d2, a2[q]);
                    a3[q] = fmaf(bf2f(v3[q]), d3, a3[q]);
                }
            }
        }
    }

    float r[EPL];
    #pragma unroll
    for (int q = 0; q < EPL; ++q) r[q] = 0.f;
    if (valid) {
        const float dd = dinv[node], dd2 = dd * dd;
        if constexpr (EPL == 8) {
            bfu8 sv = *reinterpret_cast<const bfu8*>(H + (size_t)node * F + co);
            #pragma unroll
            for (int q = 0; q < 8; ++q)
                r[q] = fmaf((a0[q] + a1[q]) + (a2[q] + a3[q]), dd,
                            fmaf(bf2f(sv[q]), dd2, bias[co + q]));
        } else {
            bfu4 sv = *reinterpret_cast<const bfu4*>(H + (size_t)node * F + co);
            #pragma unroll
            for (int q = 0; q < EPL; ++q)
                r[q] = fmaf((a0[q] + a1[q]) + (a2[q] + a3[q]), dd,
                            fmaf(bf2f(sv[q]), dd2, bias[co + q]));
        }
    }

    if constexpr (BFOUT) {
        if (valid) {
            u16* out = reinterpret_cast<u16*>(Aout) + (size_t)node * F + co;
            if constexpr (EPL == 8) {
                bfu8 o;
                #pragma unroll
                for (int q = 0; q < 8; ++q) o[q] = f2bf(fmaxf(r[q], 0.f));
                *reinterpret_cast<bfu8*>(out) = o;
            } else {
                bfu4 o;
                #pragma unroll
                for (int q = 0; q < EPL; ++q) o[q] = f2bf(fmaxf(r[q], 0.f));
                *reinterpret_cast<bfu4*>(out) = o;
            }
        }
    } else if constexpr (SUMOUT) {
        float ls = 0.f;
        if (valid) {
            float* out = reinterpret_cast<float*>(Aout) + (size_t)node * F + co;
            #pragma unroll
            for (int q = 0; q < EPL; ++q) {
                const float z = fmaxf(r[q], 0.f);
                out[q] = z;
                ls += z;
            }
        }
        const int wl = threadIdx.x & 63, wi = threadIdx.x >> 6;
        #pragma unroll
        for (int off = 32; off; off >>= 1) ls += __shfl_down(ls, off);
        __shared__ float wsum[2];
        if (wl == 0) wsum[wi] = ls;
        __syncthreads();
        if (threadIdx.x == 0)
            partials[blockIdx.x] = wsum[0] + wsum[1];
    } else {
        if (valid) {
            float* out = reinterpret_cast<float*>(Aout) + (size_t)node * F + co;
            #pragma unroll
            for (int q = 0; q < EPL; ++q) out[q] = r[q];
        }
    }
}

// ---------------- epilogue ----------------
__global__ __launch_bounds__(1024) void reduce_partials(const float* __restrict__ partials,
                                                        float* __restrict__ S, int n) {
    float local = 0.f;
    for (int i = threadIdx.x; i < n; i += 1024) local += partials[i];
    const int lane = threadIdx.x & 63, wid = threadIdx.x >> 6;
    #pragma unroll
    for (int off = 32; off; off >>= 1) local += __shfl_down(local, off);
    __shared__ float wsum[16];
    if (lane == 0) wsum[wid] = local;
    __syncthreads();
    if (threadIdx.x == 0) {
        float t = 0.f;
        #pragma unroll
        for (int i = 0; i < 16; ++i) t += wsum[i];
        *S = t;
    }
}

__global__ void final_norm(float* __restrict__ Z, const float* __restrict__ S, int N) {
    const int wid = threadIdx.x >> 6;
    const int lane = threadIdx.x & 63;
    const int row = blockIdx.x * 4 + wid;
    if (row >= N) return;
    const float inv = 1.0f / (*S);
    float v0 = Z[(size_t)row * 128 + lane] * inv;
    float v1 = Z[(size_t)row * 128 + lane + 64] * inv;
    const float t0 = tanhf(v0), t1 = tanhf(v1);
    const float y0 = t0 * t0, y1 = t1 * t1;
    float ss = y0 * y0 + y1 * y1;
    #pragma unroll
    for (int off = 32; off; off >>= 1) ss += __shfl_xor(ss, off);
    const float nrm = fmaxf(sqrtf(ss), 1e-12f);
    const float innrm = 1.0f / nrm;
    Z[(size_t)row * 128 + lane]      = y0 * innrm;
    Z[(size_t)row * 128 + lane + 64] = y1 * innrm;
}

extern "C" void kernel_launch(void* const* d_in, const int* in_sizes, int n_in,
                              void* d_out, int out_size, void* d_ws, size_t ws_size,
                              hipStream_t stream) {
    const float* x  = (const float*)d_in[0];
    const int*   ei = (const int*)d_in[1];
    const float* W1 = (const float*)d_in[2];
    const float* b1 = (const float*)d_in[3];
    const float* W2 = (const float*)d_in[4];
    const float* b2 = (const float*)d_in[5];
    const float* W3 = (const float*)d_in[6];
    const float* b3 = (const float*)d_in[7];
    float* out = (float*)d_out;

    const int N = NN, E = NE;
    const int* src = ei;
    const int* dst = ei + E;

    char* ws = (char*)d_ws;
    size_t off = 0;
    u16* bufA = (u16*)(ws + off); off += (size_t)(N + 1) * 512 * 2;
    u16* bufB = (u16*)(ws + off); off += (size_t)(N + 1) * 512 * 2;
    u16* Wt1 = (u16*)(ws + off); off += 512 * 512 * 2;
    u16* Wt2 = (u16*)(ws + off); off += 256 * 512 * 2;
    u16* Wt3 = (u16*)(ws + off); off += 128 * 256 * 2;
    float* dinv   = (float*)(ws + off); off += 204800;
    int*   cnt    = (int*)  (ws + off); off += 204800;
    float* Ssum   = (float*)(ws + off); off += 256;
    float* partials = (float*)(ws + off); off += 65536;
    int*   ell    = (int*)  (ws + off); off += (size_t)N * SLOTS * 4 + 256;

    // ---- conversions ----
    cvt_x<<<2048, 256, 0, stream>>>(x, bufA, N * 128);
    cvt_w<<<(262144 + 131072 + 32768 + 255) / 256, 256, 0, stream>>>(
        W1, Wt1, W2, Wt2, W3, Wt3);

    // ---- ELL adjacency + dinv ----
    init_ell<<<(N * SLOTS + 255) / 256, 256, 0, stream>>>(ell, cnt, N);
    build_ell<<<(E + 255) / 256, 256, 0, stream>>>(src, dst, cnt, ell, E);
    make_dinv<<<(N + 255) / 256, 256, 0, stream>>>(cnt, dinv, N);

    // ---- layer 1 ----
    gemm_bf16<4, 512><<<8 * BXPG2 * 4, 512, 0, stream>>>(bufA, Wt1, bufB, N, 512);
    aggregate_bf<512, 64, true, false><<<(N * 64 + 127) / 128, 128, 0, stream>>>(
        bufB, cnt, ell, dinv, b1, bufA, nullptr, N);
    // ---- layer 2 ----
    gemm_bf16<2, 512><<<8 * BXPG2 * 2, 512, 0, stream>>>(bufA, Wt2, bufB, N, 256);
    aggregate_bf<256, 32, true, false><<<(N * 32 + 127) / 128, 128, 0, stream>>>(
        bufB, cnt, ell, dinv, b2, bufA, nullptr, N);
    // ---- layer 3 ----
    gemm_bf16<1, 256><<<8 * BXPG2 * 1, 512, 0, stream>>>(bufA, Wt3, bufB, N, 128);
    const int aggBlocks3 = (N * 16 + 127) / 128;
    aggregate_bf<128, 16, false, true><<<aggBlocks3, 128, 0, stream>>>(
        bufB, cnt, ell, dinv, b3, out, partials, N);

    // ---- epilogue ----
    reduce_partials<<<1, 1024, 0, stream>>>(partials, Ssum, aggBlocks3);
    final_norm<<<(N + 3) / 4, 256, 0, stream>>>(out, Ssum, N);
}

// Round 20
// 258.670 us; speedup vs baseline: 1.0717x; 1.0717x over previous
//
#include <hip/hip_runtime.h>
#include <math.h>

#define NN 50000
#define NE 400000
#define SLOTS 32
#define MT2 196       // (NN+255)/256 row tiles
#define BXPG2 25      // ceil(MT2/8) row tiles per XCD group

typedef unsigned short u16;
typedef __bf16 bf16x8 __attribute__((ext_vector_type(8)));
typedef float f32x4 __attribute__((ext_vector_type(4)));
typedef unsigned int u32x4 __attribute__((ext_vector_type(4)));
typedef u16 bfu8 __attribute__((ext_vector_type(8)));
typedef u16 bfu4 __attribute__((ext_vector_type(4)));

__device__ __forceinline__ u16 f2bf(float f) {
    unsigned u = __builtin_bit_cast(unsigned, f);
    u += 0x7fff + ((u >> 16) & 1);
    return (u16)(u >> 16);
}
__device__ __forceinline__ float bf2f(u16 h) {
    unsigned u = ((unsigned)h) << 16;
    return __builtin_bit_cast(float, u);
}

__device__ __forceinline__ void gload_lds16(const void* g, void* l) {
    typedef __attribute__((address_space(1))) const unsigned int GU;
    typedef __attribute__((address_space(3))) unsigned int LU;
    __builtin_amdgcn_global_load_lds((GU*)g, (LU*)l, 16, 0, 0);
}

// ---------------- weight conversions (x handled in-GEMM) ----------------
__global__ void cvt_w(const float* __restrict__ W1, u16* __restrict__ Wt1,
                      const float* __restrict__ W2, u16* __restrict__ Wt2,
                      const float* __restrict__ W3, u16* __restrict__ Wt3) {
    int idx = blockIdx.x * blockDim.x + threadIdx.x;
    if (idx < 262144) {
        int n = idx >> 9, k = idx & 511;
        Wt1[idx] = f2bf(W1[(size_t)k * 512 + n]);
        return;
    }
    idx -= 262144;
    if (idx < 131072) {
        int n = idx >> 9, k = idx & 511;
        Wt2[idx] = f2bf(W2[(size_t)k * 256 + n]);
        return;
    }
    idx -= 131072;
    if (idx < 32768) {
        int n = idx >> 8, k = idx & 255;
        Wt3[idx] = f2bf(W3[(size_t)k * 128 + n]);
    }
}

// ---------------- ELL build ----------------
__global__ void init_ell(int* __restrict__ ell, int* __restrict__ cnt, int N) {
    int i = blockIdx.x * blockDim.x + threadIdx.x;
    const int total4 = N * SLOTS / 4;
    if (i < total4) {
        int4 v = make_int4(N, N, N, N);
        reinterpret_cast<int4*>(ell)[i] = v;
    }
    if (i < N) cnt[i] = 0;
}

__global__ void build_ell(const int* __restrict__ src, const int* __restrict__ dst,
                          int* __restrict__ cnt, int* __restrict__ ell, int E) {
    int e = blockIdx.x * blockDim.x + threadIdx.x;
    if (e < E) {
        const int d = dst[e];
        int pos = atomicAdd(&cnt[d], 1);
        if (pos < SLOTS) ell[d * SLOTS + pos] = src[e];
    }
}

__global__ void make_dinv(const int* __restrict__ cnt, float* __restrict__ dinv, int N) {
    int i = blockIdx.x * blockDim.x + threadIdx.x;
    if (i < N) dinv[i] = rsqrtf(1.0f + (float)cnt[i]);
    if (i == 0) dinv[N] = 0.f;
}

// ---------------- bf16 MFMA GEMM: H = X @ Wt^T, BM=256 x BN=128, 8 waves ----
// XCD-grouped decode, 2-phase dbuf, one vmcnt(0)+barrier per K-step.
// CVT=0: X bf16, A via global_load_lds.  LDS: A 2x16K @0, B 2x8K @32768 (48K).
// CVT=1: X f32, A staged as f32 via DMA; cvt_pk at fragment read.
//        LDS: A 2x32K @0, B 2x8K @65536 (80K).
template <int NT, int CVT, int KK>
__global__ __launch_bounds__(512) void gemm_bf16(
    const void* __restrict__ Xv, const u16* __restrict__ Wt,
    u16* __restrict__ H, int N, int NO)
{
    const int k8 = blockIdx.x & 7;
    const int idx = blockIdx.x >> 3;
    const int bx = k8 * BXPG2 + idx / NT;
    const int nt = idx - (idx / NT) * NT;
    const int m0 = bx * 256;
    if (m0 >= N) return;
    const int n0 = nt * 128;

    const u16* X = (const u16*)Xv;
    const float* Xf = (const float*)Xv;

    __shared__ unsigned char lds[CVT ? 81920 : 49152];
    const int tid = threadIdx.x;
    const int w = tid >> 6;
    const int lane = tid & 63;
    const int wr = w >> 1;
    const int wc = w & 1;

    f32x4 acc[4][4] = {};

    // B staging map (both paths): 8192B tile, 1 load/thread
    const int brow = tid >> 2;
    const int bgcol = (((tid & 3) ^ (brow & 3)) << 3);
    const int bgrow = n0 + brow;

    if constexpr (CVT) {
        // ---------- f32-DMA staged path ----------
        const int gcolf = (((tid & 7) ^ ((tid >> 3) & 7)) << 2);
        int agrow4[4];
        #pragma unroll
        for (int i = 0; i < 4; ++i) {
            int rr = m0 + i * 64 + (tid >> 3);
            agrow4[i] = (rr < N) ? rr : N - 1;
        }

        #pragma unroll
        for (int i = 0; i < 4; ++i)
            gload_lds16(Xf + (size_t)agrow4[i] * KK + gcolf,
                        lds + i * 8192 + w * 1024);
        gload_lds16(Wt + (size_t)bgrow * KK + bgcol, lds + 65536 + w * 1024);
        asm volatile("s_waitcnt vmcnt(0)" ::: "memory");
        __syncthreads();

        int cur = 0;
        for (int k0 = 0; k0 < KK; k0 += 32) {
            const bool more = (k0 + 32 < KK);
            if (more) {
                const int na = (cur ^ 1) * 32768;
                const int nb = 65536 + (cur ^ 1) * 8192;
                #pragma unroll
                for (int i = 0; i < 4; ++i)
                    gload_lds16(Xf + (size_t)agrow4[i] * KK + k0 + 32 + gcolf,
                                lds + na + i * 8192 + w * 1024);
                gload_lds16(Wt + (size_t)bgrow * KK + k0 + 32 + bgcol,
                            lds + nb + w * 1024);
            }

            const int ca = cur * 32768;
            const int cbb = 65536 + cur * 8192;
            bf16x8 af[4], bfr[4];
            #pragma unroll
            for (int m = 0; m < 4; ++m) {
                const int r = wr * 64 + m * 16 + (lane & 15);
                const int g = lane >> 4;
                const int j0 = (2 * g) ^ (r & 7);
                const int j1 = (2 * g + 1) ^ (r & 7);
                const f32x4 lo = *reinterpret_cast<const f32x4*>(lds + ca + r * 128 + j0 * 16);
                const f32x4 hi = *reinterpret_cast<const f32x4*>(lds + ca + r * 128 + j1 * 16);
                unsigned q0, q1, q2, q3;
                asm("v_cvt_pk_bf16_f32 %0, %1, %2" : "=v"(q0) : "v"(lo[0]), "v"(lo[1]));
                asm("v_cvt_pk_bf16_f32 %0, %1, %2" : "=v"(q1) : "v"(lo[2]), "v"(lo[3]));
                asm("v_cvt_pk_bf16_f32 %0, %1, %2" : "=v"(q2) : "v"(hi[0]), "v"(hi[1]));
                asm("v_cvt_pk_bf16_f32 %0, %1, %2" : "=v"(q3) : "v"(hi[2]), "v"(hi[3]));
                u32x4 t; t[0] = q0; t[1] = q1; t[2] = q2; t[3] = q3;
                af[m] = __builtin_bit_cast(bf16x8, t);
            }
            #pragma unroll
            for (int n = 0; n < 4; ++n) {
                const int r = wc * 64 + n * 16 + (lane & 15);
                const int off = cbb + r * 64 + (((lane >> 4) ^ (r & 3)) * 16);
                bfr[n] = *reinterpret_cast<const bf16x8*>(lds + off);
            }
            #pragma unroll
            for (int m = 0; m < 4; ++m)
                #pragma unroll
                for (int n = 0; n < 4; ++n)
                    acc[m][n] = __builtin_amdgcn_mfma_f32_16x16x32_bf16(
                        af[m], bfr[n], acc[m][n], 0, 0, 0);

            asm volatile("s_waitcnt vmcnt(0)" ::: "memory");
            __syncthreads();
            cur ^= 1;
        }
    } else {
        // ---------- bf16 dma path ----------
        const int gcol = (((tid & 3) ^ ((tid >> 2) & 3)) << 3);
        int agrow2[2];
        #pragma unroll
        for (int i = 0; i < 2; ++i) {
            int rr = m0 + i * 128 + (tid >> 2);
            agrow2[i] = (rr < N) ? rr : N - 1;
        }

        #pragma unroll
        for (int i = 0; i < 2; ++i)
            gload_lds16(X + (size_t)agrow2[i] * KK + gcol,
                        lds + i * 8192 + w * 1024);
        gload_lds16(Wt + (size_t)bgrow * KK + bgcol, lds + 32768 + w * 1024);
        asm volatile("s_waitcnt vmcnt(0)" ::: "memory");
        __syncthreads();

        int cur = 0;
        for (int k0 = 0; k0 < KK; k0 += 32) {
            const bool more = (k0 + 32 < KK);
            if (more) {
                const int na = (cur ^ 1) * 16384;
                const int nb = 32768 + (cur ^ 1) * 8192;
                #pragma unroll
                for (int i = 0; i < 2; ++i)
                    gload_lds16(X + (size_t)agrow2[i] * KK + k0 + 32 + gcol,
                                lds + na + i * 8192 + w * 1024);
                gload_lds16(Wt + (size_t)bgrow * KK + k0 + 32 + bgcol,
                            lds + nb + w * 1024);
            }

            const int ca = cur * 16384;
            const int cbb = 32768 + cur * 8192;
            bf16x8 af[4], bfr[4];
            #pragma unroll
            for (int m = 0; m < 4; ++m) {
                const int r = wr * 64 + m * 16 + (lane & 15);
                const int off = ca + r * 64 + (((lane >> 4) ^ (r & 3)) * 16);
                af[m] = *reinterpret_cast<const bf16x8*>(lds + off);
            }
            #pragma unroll
            for (int n = 0; n < 4; ++n) {
                const int r = wc * 64 + n * 16 + (lane & 15);
                const int off = cbb + r * 64 + (((lane >> 4) ^ (r & 3)) * 16);
                bfr[n] = *reinterpret_cast<const bf16x8*>(lds + off);
            }
            #pragma unroll
            for (int m = 0; m < 4; ++m)
                #pragma unroll
                for (int n = 0; n < 4; ++n)
                    acc[m][n] = __builtin_amdgcn_mfma_f32_16x16x32_bf16(
                        af[m], bfr[n], acc[m][n], 0, 0, 0);

            asm volatile("s_waitcnt vmcnt(0)" ::: "memory");
            __syncthreads();
            cur ^= 1;
        }
    }

    // epilogue: 4 quadrant passes (row-half rh x col-half c) via 33792B Cs
    float* Cs = reinterpret_cast<float*>(lds);
    #pragma unroll
    for (int rh = 0; rh < 2; ++rh) {
        #pragma unroll
        for (int c = 0; c < 2; ++c) {
            __syncthreads();
            if ((wr >> 1) == rh && wc == c) {
                const int rbase = (wr & 1) * 64;
                #pragma unroll
                for (int m = 0; m < 4; ++m)
                    #pragma unroll
                    for (int n = 0; n < 4; ++n)
                        #pragma unroll
                        for (int r = 0; r < 4; ++r) {
                            int row = rbase + m * 16 + (lane >> 4) * 4 + r;
                            int col = n * 16 + (lane & 15);
                            Cs[row * 66 + col] = acc[m][n][r];
                        }
            }
            __syncthreads();
            const int row = tid >> 2;        // 0..127
            const int q = tid & 3;           // 16-col quarter
            const int grow = m0 + rh * 128 + row;
            if (grow < N) {
                const float* p = Cs + row * 66 + q * 16;
                bfu8 oA, oB;
                #pragma unroll
                for (int j = 0; j < 8; ++j) oA[j] = f2bf(p[j]);
                #pragma unroll
                for (int j = 0; j < 8; ++j) oB[j] = f2bf(p[8 + j]);
                bfu8* dst = reinterpret_cast<bfu8*>(H + (size_t)grow * NO + n0 + c * 64 + q * 16);
                dst[0] = oA; dst[1] = oB;
            }
        }
    }
}

// ---------------- ELL pull-aggregate (bf16 H), 4-way MLP, 16B/lane ---------
template <int F, int LPN, bool BFOUT, bool SUMOUT>
__global__ __launch_bounds__(128) void aggregate_bf(
    const u16* __restrict__ H, const int* __restrict__ cnt,
    const int* __restrict__ ell, const float* __restrict__ dinv,
    const float* __restrict__ bias, void* __restrict__ Aout,
    float* __restrict__ partials, int N)
{
    constexpr int EPL = F / LPN;
    const int gtid = blockIdx.x * blockDim.x + threadIdx.x;
    const int node = gtid / LPN;
    const int lane = gtid - node * LPN;
    const int co = lane * EPL;
    const bool valid = node < N;

    float a0[EPL], a1[EPL], a2[EPL], a3[EPL];
    #pragma unroll
    for (int q = 0; q < EPL; ++q) { a0[q] = 0.f; a1[q] = 0.f; a2[q] = 0.f; a3[q] = 0.f; }

    if (valid) {
        const int base = node * SLOTS;
        const int c = min(cnt[node], SLOTS);
        const int pd = (c + 3) & ~3;
        for (int j = 0; j < pd; j += 4) {
            const int4 s4 = *reinterpret_cast<const int4*>(ell + base + j);
            const float d0 = dinv[s4.x];
            const float d1 = dinv[s4.y];
            const float d2 = dinv[s4.z];
            const float d3 = dinv[s4.w];
            if constexpr (EPL == 8) {
                bfu8 v0 = *reinterpret_cast<const bfu8*>(H + (size_t)s4.x * F + co);
                bfu8 v1 = *reinterpret_cast<const bfu8*>(H + (size_t)s4.y * F + co);
                bfu8 v2 = *reinterpret_cast<const bfu8*>(H + (size_t)s4.z * F + co);
                bfu8 v3 = *reinterpret_cast<const bfu8*>(H + (size_t)s4.w * F + co);
                #pragma unroll
                for (int q = 0; q < 8; ++q) {
                    a0[q] = fmaf(bf2f(v0[q]), d0, a0[q]);
                    a1[q] = fmaf(bf2f(v1[q]), d1, a1[q]);
                    a2[q] = fmaf(bf2f(v2[q]), d2, a2[q]);
                    a3[q] = fmaf(bf2f(v3[q]), d3, a3[q]);
                }
            } else {
                bfu4 v0 = *reinterpret_cast<const bfu4*>(H + (size_t)s4.x * F + co);
                bfu4 v1 = *reinterpret_cast<const bfu4*>(H + (size_t)s4.y * F + co);
                bfu4 v2 = *reinterpret_cast<const bfu4*>(H + (size_t)s4.z * F + co);
                bfu4 v3 = *reinterpret_cast<const bfu4*>(H + (size_t)s4.w * F + co);
                #pragma unroll
                for (int q = 0; q < EPL; ++q) {
                    a0[q] = fmaf(bf2f(v0[q]), d0, a0[q]);
                    a1[q] = fmaf(bf2f(v1[q]), d1, a1[q]);
                    a2[q] = fmaf(bf2f(v2[q]), d2, a2[q]);
                    a3[q] = fmaf(bf2f(v3[q]), d3, a3[q]);
                }
            }
        }
    }

    float r[EPL];
    #pragma unroll
    for (int q = 0; q < EPL; ++q) r[q] = 0.f;
    if (valid) {
        const float dd = dinv[node], dd2 = dd * dd;
        if constexpr (EPL == 8) {
            bfu8 sv = *reinterpret_cast<const bfu8*>(H + (size_t)node * F + co);
            #pragma unroll
            for (int q = 0; q < 8; ++q)
                r[q] = fmaf((a0[q] + a1[q]) + (a2[q] + a3[q]), dd,
                            fmaf(bf2f(sv[q]), dd2, bias[co + q]));
        } else {
            bfu4 sv = *reinterpret_cast<const bfu4*>(H + (size_t)node * F + co);
            #pragma unroll
            for (int q = 0; q < EPL; ++q)
                r[q] = fmaf((a0[q] + a1[q]) + (a2[q] + a3[q]), dd,
                            fmaf(bf2f(sv[q]), dd2, bias[co + q]));
        }
    }

    if constexpr (BFOUT) {
        if (valid) {
            u16* out = reinterpret_cast<u16*>(Aout) + (size_t)node * F + co;
            if constexpr (EPL == 8) {
                bfu8 o;
                #pragma unroll
                for (int q = 0; q < 8; ++q) o[q] = f2bf(fmaxf(r[q], 0.f));
                *reinterpret_cast<bfu8*>(out) = o;
            } else {
                bfu4 o;
                #pragma unroll
                for (int q = 0; q < EPL; ++q) o[q] = f2bf(fmaxf(r[q], 0.f));
                *reinterpret_cast<bfu4*>(out) = o;
            }
        }
    } else if constexpr (SUMOUT) {
        float ls = 0.f;
        if (valid) {
            float* out = reinterpret_cast<float*>(Aout) + (size_t)node * F + co;
            #pragma unroll
            for (int q = 0; q < EPL; ++q) {
                const float z = fmaxf(r[q], 0.f);
                out[q] = z;
                ls += z;
            }
        }
        const int wl = threadIdx.x & 63, wi = threadIdx.x >> 6;
        #pragma unroll
        for (int off = 32; off; off >>= 1) ls += __shfl_down(ls, off);
        __shared__ float wsum[2];
        if (wl == 0) wsum[wi] = ls;
        __syncthreads();
        if (threadIdx.x == 0)
            partials[blockIdx.x] = wsum[0] + wsum[1];
    } else {
        if (valid) {
            float* out = reinterpret_cast<float*>(Aout) + (size_t)node * F + co;
            #pragma unroll
            for (int q = 0; q < EPL; ++q) out[q] = r[q];
        }
    }
}

// ---------------- epilogue ----------------
__global__ __launch_bounds__(1024) void reduce_partials(const float* __restrict__ partials,
                                                        float* __restrict__ S, int n) {
    float local = 0.f;
    for (int i = threadIdx.x; i < n; i += 1024) local += partials[i];
    const int lane = threadIdx.x & 63, wid = threadIdx.x >> 6;
    #pragma unroll
    for (int off = 32; off; off >>= 1) local += __shfl_down(local, off);
    __shared__ float wsum[16];
    if (lane == 0) wsum[wid] = local;
    __syncthreads();
    if (threadIdx.x == 0) {
        float t = 0.f;
        #pragma unroll
        for (int i = 0; i < 16; ++i) t += wsum[i];
        *S = t;
    }
}

__global__ void final_norm(float* __restrict__ Z, const float* __restrict__ S, int N) {
    const int wid = threadIdx.x >> 6;
    const int lane = threadIdx.x & 63;
    const int row = blockIdx.x * 4 + wid;
    if (row >= N) return;
    const float inv = 1.0f / (*S);
    float v0 = Z[(size_t)row * 128 + lane] * inv;
    float v1 = Z[(size_t)row * 128 + lane + 64] * inv;
    const float t0 = tanhf(v0), t1 = tanhf(v1);
    const float y0 = t0 * t0, y1 = t1 * t1;
    float ss = y0 * y0 + y1 * y1;
    #pragma unroll
    for (int off = 32; off; off >>= 1) ss += __shfl_xor(ss, off);
    const float nrm = fmaxf(sqrtf(ss), 1e-12f);
    const float innrm = 1.0f / nrm;
    Z[(size_t)row * 128 + lane]      = y0 * innrm;
    Z[(size_t)row * 128 + lane + 64] = y1 * innrm;
}

extern "C" void kernel_launch(void* const* d_in, const int* in_sizes, int n_in,
                              void* d_out, int out_size, void* d_ws, size_t ws_size,
                              hipStream_t stream) {
    const float* x  = (const float*)d_in[0];
    const int*   ei = (const int*)d_in[1];
    const float* W1 = (const float*)d_in[2];
    const float* b1 = (const float*)d_in[3];
    const float* W2 = (const float*)d_in[4];
    const float* b2 = (const float*)d_in[5];
    const float* W3 = (const float*)d_in[6];
    const float* b3 = (const float*)d_in[7];
    float* out = (float*)d_out;

    const int N = NN, E = NE;
    const int* src = ei;
    const int* dst = ei + E;

    char* ws = (char*)d_ws;
    size_t off = 0;
    u16* bufA = (u16*)(ws + off); off += (size_t)(N + 1) * 512 * 2;
    u16* bufB = (u16*)(ws + off); off += (size_t)(N + 1) * 512 * 2;
    u16* Wt1 = (u16*)(ws + off); off += 512 * 512 * 2;
    u16* Wt2 = (u16*)(ws + off); off += 256 * 512 * 2;
    u16* Wt3 = (u16*)(ws + off); off += 128 * 256 * 2;
    float* dinv   = (float*)(ws + off); off += 204800;
    int*   cnt    = (int*)  (ws + off); off += 204800;
    float* Ssum   = (float*)(ws + off); off += 256;
    float* partials = (float*)(ws + off); off += 65536;
    int*   ell    = (int*)  (ws + off); off += (size_t)N * SLOTS * 4 + 256;

    // ---- weight conversions ----
    cvt_w<<<(262144 + 131072 + 32768 + 255) / 256, 256, 0, stream>>>(
        W1, Wt1, W2, Wt2, W3, Wt3);

    // ---- ELL adjacency + dinv ----
    init_ell<<<(N * SLOTS / 4 + 255) / 256, 256, 0, stream>>>(ell, cnt, N);
    build_ell<<<(E + 255) / 256, 256, 0, stream>>>(src, dst, cnt, ell, E);
    make_dinv<<<(N + 255) / 256, 256, 0, stream>>>(cnt, dinv, N);

    // ---- layer 1 (f32 x staged via DMA, cvt on fragment read) ----
    gemm_bf16<4, 1, 512><<<8 * BXPG2 * 4, 512, 0, stream>>>(x, Wt1, bufB, N, 512);
    aggregate_bf<512, 64, true, false><<<(N * 64 + 127) / 128, 128, 0, stream>>>(
        bufB, cnt, ell, dinv, b1, bufA, nullptr, N);
    // ---- layer 2 ----
    gemm_bf16<2, 0, 512><<<8 * BXPG2 * 2, 512, 0, stream>>>(bufA, Wt2, bufB, N, 256);
    aggregate_bf<256, 32, true, false><<<(N * 32 + 127) / 128, 128, 0, stream>>>(
        bufB, cnt, ell, dinv, b2, bufA, nullptr, N);
    // ---- layer 3 ----
    gemm_bf16<1, 0, 256><<<8 * BXPG2 * 1, 512, 0, stream>>>(bufA, Wt3, bufB, N, 128);
    const int aggBlocks3 = (N * 16 + 127) / 128;
    aggregate_bf<128, 16, false, true><<<aggBlocks3, 128, 0, stream>>>(
        bufB, cnt, ell, dinv, b3, out, partials, N);

    // ---- epilogue ----
    reduce_partials<<<1, 1024, 0, stream>>>(partials, Ssum, aggBlocks3);
    final_norm<<<(N + 3) / 4, 256, 0, stream>>>(out, Ssum, N);
}